// Round 10
// baseline (174.500 us; speedup 1.0000x reference)
//
#include <hip/hip_runtime.h>
#include <hip/hip_bf16.h>
#include <math.h>

#define DIM   5120
#define NH    40
#define NKV   8
#define HD    128
#define BS    8
#define KLEN  4096
#define NEWT  4095
#define NREP  5

#define ODQKV 7168          // 5120 + 1024 + 1024 combined output columns
#define NKC   128           // split-K chunks for GEMVs (occupancy-sized)
#define KCH   (DIM / NKC)   // 40 rows per chunk

#define NCHB  128               // t-chunks per batch = blocks per batch
#define CH_T  (KLEN / NCHB)     // 32 t per block
#define NPART NCHB              // partials per (b,h)

// workspace layout (in floats)
#define WS_Q       0
#define WS_K       (WS_Q + BS * DIM)        // 40960
#define WS_V       (WS_K + BS * NKV * HD)   // 49152
#define WS_ATTN    (WS_V + BS * NKV * HD)   // 57344
#define WS_SCRATCH (WS_ATTN + BS * DIM)     // 98304  (scratch reused across phases)

// ---------------------------------------------------------------------------
// Phase A: combined QKV GEMV, split-K partials. 2 cols/thread, float2 weight
// loads, x via wave-uniform scalar loads. grid = 14 * NKC blocks.
// ---------------------------------------------------------------------------
__global__ __launch_bounds__(256) void qkv_partial_k(
    const float* __restrict__ x, const float* __restrict__ wq,
    const float* __restrict__ wk, const float* __restrict__ wv,
    float* __restrict__ part) {
  const int cb = blockIdx.x % 14;
  const int kc = blockIdx.x / 14;
  const int c0 = cb * 512 + threadIdx.x * 2;   // first of 2 owned columns

  const float* w; int OD, j;
  if (c0 < 5120)      { w = wq; OD = 5120; j = c0; }
  else if (c0 < 6144) { w = wk; OD = 1024; j = c0 - 5120; }
  else                { w = wv; OD = 1024; j = c0 - 6144; }

  const int i0 = kc * KCH;
  float ax[BS], ay[BS];
#pragma unroll
  for (int b = 0; b < BS; ++b) { ax[b] = 0.f; ay[b] = 0.f; }

  const float* wp = w + (size_t)i0 * OD + j;
  const float* xp = x + i0;
#pragma unroll 4
  for (int ii = 0; ii < KCH; ++ii) {
    const float2 wv2 = *(const float2*)&wp[(size_t)ii * OD];
#pragma unroll
    for (int b = 0; b < BS; ++b) {
      const float xb = xp[b * DIM + ii];   // wave-uniform -> scalar load
      ax[b] = fmaf(xb, wv2.x, ax[b]);
      ay[b] = fmaf(xb, wv2.y, ay[b]);
    }
  }
#pragma unroll
  for (int b = 0; b < BS; ++b)
    *(float2*)&part[((size_t)kc * BS + b) * ODQKV + c0] = make_float2(ax[b], ay[b]);
}

// ---------------------------------------------------------------------------
// Phase A2: reduce partials, add bias, apply RoPE (pos 4095), fold 1/sqrt(128)
// into q.
// ---------------------------------------------------------------------------
__global__ __launch_bounds__(256) void qkv_reduce_k(
    const float* __restrict__ part, const float* __restrict__ bq,
    const float* __restrict__ bk, const float* __restrict__ bv,
    const float* __restrict__ fc, float* __restrict__ qws,
    float* __restrict__ kws, float* __restrict__ vws) {
  int g = blockIdx.x * 256 + threadIdx.x;
  if (g >= BS * (ODQKV / 2)) return;
  int b  = g / (ODQKV / 2);
  int cp = g - b * (ODQKV / 2);
  int c0 = cp * 2;

  float sx = 0.f, sy = 0.f;
  for (int kc = 0; kc < NKC; ++kc) {
    const float2 p = *(const float2*)&part[((size_t)kc * BS + b) * ODQKV + c0];
    sx += p.x; sy += p.y;
  }

  const float scale = 0.088388347648318447f;  // 1/sqrt(128)
  if (c0 < 5120) {
    sx += bq[c0]; sy += bq[c0 + 1];
    int jf = (c0 & 127) >> 1;
    float cs = fc[2 * jf], sn = fc[2 * jf + 1];
    qws[b * DIM + c0]     = (sx * cs - sy * sn) * scale;
    qws[b * DIM + c0 + 1] = (sx * sn + sy * cs) * scale;
  } else if (c0 < 6144) {
    int jj = c0 - 5120;
    sx += bk[jj]; sy += bk[jj + 1];
    int jf = (jj & 127) >> 1;
    float cs = fc[2 * jf], sn = fc[2 * jf + 1];
    kws[b * NKV * HD + jj]     = sx * cs - sy * sn;
    kws[b * NKV * HD + jj + 1] = sx * sn + sy * cs;
  } else {
    int jj = c0 - 6144;
    vws[b * NKV * HD + jj]     = sx + bv[jj];
    vws[b * NKV * HD + jj + 1] = sy + bv[jj + 1];
  }
}

// ---------------------------------------------------------------------------
// Phase B: flash-decode partials, DENSE-STREAMING layout (r8 structure,
// VGPR<=64), occupancy-sized grid: BS*NCHB = 1024 blocks x 8 waves =
// 32 waves/CU cap. Block = (b, 32-t chunk), wave w = kv head. Lane L:
// half=L>>5 picks t parity, j32=L&31 owns d=[4*j32,4*j32+4). Branchless
// online softmax; xor-32 merge. No LDS. Tail t=4095 peeled.
// ---------------------------------------------------------------------------
__global__ __launch_bounds__(512) void attn_partial_k(
    const float* __restrict__ ck, const float* __restrict__ cv,
    const float* __restrict__ qws, const float* __restrict__ kws,
    const float* __restrict__ vws, float* __restrict__ pM,
    float* __restrict__ pL, float* __restrict__ pO) {
  const int blk   = blockIdx.x;
  const int chunk = blk & (NCHB - 1);
  const int b     = blk / NCHB;
  const int w     = threadIdx.x >> 6;    // wave index = kv head
  const int lane  = threadIdx.x & 63;
  const int half  = lane >> 5;           // t parity within a step
  const int j32   = lane & 31;           // d-chunk [4*j32, 4*j32+4)
  const int t0    = chunk * CH_T;

  float4 q[NREP];
#pragma unroll
  for (int r = 0; r < NREP; ++r)
    q[r] = *(const float4*)&qws[b * DIM + (w * NREP + r) * HD + 4 * j32];

  float m[NREP], l[NREP];
  float4 o[NREP];
#pragma unroll
  for (int r = 0; r < NREP; ++r) {
    m[r] = -1e30f; l[r] = 0.f; o[r] = make_float4(0.f, 0.f, 0.f, 0.f);
  }

  const float* kbase = &ck[((size_t)b * KLEN * NKV + w) * HD];
  const float* vbase = &cv[((size_t)b * KLEN * NKV + w) * HD];

  auto step = [&](const float4 k4, const float4 v4) {
    float s[NREP];
#pragma unroll
    for (int r = 0; r < NREP; ++r)
      s[r] = q[r].x * k4.x + q[r].y * k4.y + q[r].z * k4.z + q[r].w * k4.w;
#pragma unroll
    for (int off = 1; off < 32; off <<= 1) {
#pragma unroll
      for (int r = 0; r < NREP; ++r) s[r] += __shfl_xor(s[r], off, 64);
    }
#pragma unroll
    for (int r = 0; r < NREP; ++r) {
      float mn = fmaxf(m[r], s[r]);
      float p  = __expf(s[r] - mn);
      float rs = __expf(m[r] - mn);
      l[r] = fmaf(l[r], rs, p);
      o[r].x = fmaf(p, v4.x, o[r].x * rs);
      o[r].y = fmaf(p, v4.y, o[r].y * rs);
      o[r].z = fmaf(p, v4.z, o[r].z * rs);
      o[r].w = fmaf(p, v4.w, o[r].w * rs);
      m[r] = mn;
    }
  };

  const bool tailb = (chunk == NCHB - 1);
  const int  niter = tailb ? (CH_T / 2 - 1) : (CH_T / 2);   // 15 or 16 steps

  const float* kp = kbase + (size_t)(t0 + half) * (NKV * HD) + 4 * j32;
  const float* vp = vbase + (size_t)(t0 + half) * (NKV * HD) + 4 * j32;
#pragma unroll 4
  for (int i = 0; i < niter; ++i) {
    const float4 k4 = *(const float4*)kp;
    const float4 v4 = *(const float4*)vp;
    kp += 2 * NKV * HD;
    vp += 2 * NKV * HD;
    step(k4, v4);
  }
  if (tailb) {
    const int t = t0 + CH_T - 2 + half;            // 4094, 4095
    const float* kr = (t == NEWT) ? &kws[(b * NKV + w) * HD]
                                  : kbase + (size_t)t * (NKV * HD);
    const float* vr = (t == NEWT) ? &vws[(b * NKV + w) * HD]
                                  : vbase + (size_t)t * (NKV * HD);
    step(*(const float4*)(kr + 4 * j32), *(const float4*)(vr + 4 * j32));
  }

  // merge the two t-parity halves (lanes L and L^32 hold the same d-range)
#pragma unroll
  for (int r = 0; r < NREP; ++r) {
    float  mo = __shfl_xor(m[r], 32, 64);
    float  lo = __shfl_xor(l[r], 32, 64);
    float4 oo;
    oo.x = __shfl_xor(o[r].x, 32, 64);
    oo.y = __shfl_xor(o[r].y, 32, 64);
    oo.z = __shfl_xor(o[r].z, 32, 64);
    oo.w = __shfl_xor(o[r].w, 32, 64);
    float mn = fmaxf(m[r], mo);
    float ea = __expf(m[r] - mn);
    float eb = __expf(mo - mn);
    l[r] = l[r] * ea + lo * eb;
    o[r].x = o[r].x * ea + oo.x * eb;
    o[r].y = o[r].y * ea + oo.y * eb;
    o[r].z = o[r].z * ea + oo.z * eb;
    o[r].w = o[r].w * ea + oo.w * eb;
    m[r] = mn;
  }

  const int pb = (b * NKV + w) * NCHB + chunk;
  if (half == 0) {
#pragma unroll
    for (int r = 0; r < NREP; ++r)
      *(float4*)&pO[((size_t)pb * NREP + r) * HD + 4 * j32] = o[r];
    if (j32 == 0) {
#pragma unroll
      for (int r = 0; r < NREP; ++r) {
        pM[pb * NREP + r] = m[r];
        pL[pb * NREP + r] = l[r];
      }
    }
  }
}

// ---------------------------------------------------------------------------
// Phase B2: combine NPART partials per (b,h) with exp rescale.
// ---------------------------------------------------------------------------
__global__ __launch_bounds__(256) void attn_combine_k(
    const float* __restrict__ pM, const float* __restrict__ pL,
    const float* __restrict__ pO, float* __restrict__ attn) {
  const int bh  = blockIdx.x;
  const int h   = bh & (NKV - 1);
  const int b   = bh / NKV;
  const int tid = threadIdx.x;
  __shared__ float ml[NREP * NPART], ll[NREP * NPART];
  __shared__ float wgt[NREP * NPART];
  __shared__ float Linv[NREP];

  for (int idx = tid; idx < NREP * NPART; idx += 256) {
    int r = idx / NPART, w = idx - r * NPART;
    ml[idx] = pM[(bh * NPART + w) * NREP + r];
    ll[idx] = pL[(bh * NPART + w) * NREP + r];
  }
  __syncthreads();
  for (int idx = tid; idx < NREP * NPART; idx += 256) {
    int r = idx / NPART;
    float M = -1e30f;
    for (int w = 0; w < NPART; ++w) M = fmaxf(M, ml[r * NPART + w]);
    float e = __expf(ml[idx] - M);
    wgt[idx] = e;
    ll[idx] *= e;
  }
  __syncthreads();
  if (tid < NREP) {
    float L = 0.f;
    for (int w = 0; w < NPART; ++w) L += ll[tid * NPART + w];
    Linv[tid] = 1.f / L;
  }
  __syncthreads();

  for (int oidx = tid; oidx < NREP * HD; oidx += 256) {
    int r = oidx >> 7, d = oidx & 127;
    float acc = 0.f;
    for (int w = 0; w < NPART; ++w)
      acc += wgt[r * NPART + w] * pO[((size_t)(bh * NPART + w) * NREP + r) * HD + d];
    attn[b * DIM + (h * NREP + r) * HD + d] = acc * Linv[r];
  }
}

// ---------------------------------------------------------------------------
// Phase C: output projection GEMV (split-K, 2 cols/thread) + reduce with bias.
// grid = 10 * NKC blocks.
// ---------------------------------------------------------------------------
__global__ __launch_bounds__(256) void out_partial_k(
    const float* __restrict__ attn, const float* __restrict__ wo,
    float* __restrict__ part) {
  const int cb = blockIdx.x % 10;
  const int kc = blockIdx.x / 10;
  const int c0 = cb * 512 + threadIdx.x * 2;

  const int i0 = kc * KCH;
  float ax[BS], ay[BS];
#pragma unroll
  for (int b = 0; b < BS; ++b) { ax[b] = 0.f; ay[b] = 0.f; }

  const float* wp = wo + (size_t)i0 * DIM + c0;
  const float* xp = attn + i0;
#pragma unroll 4
  for (int ii = 0; ii < KCH; ++ii) {
    const float2 wv2 = *(const float2*)&wp[(size_t)ii * DIM];
#pragma unroll
    for (int b = 0; b < BS; ++b) {
      const float xb = xp[b * DIM + ii];   // wave-uniform -> scalar load
      ax[b] = fmaf(xb, wv2.x, ax[b]);
      ay[b] = fmaf(xb, wv2.y, ay[b]);
    }
  }
#pragma unroll
  for (int b = 0; b < BS; ++b)
    *(float2*)&part[((size_t)kc * BS + b) * DIM + c0] = make_float2(ax[b], ay[b]);
}

__global__ __launch_bounds__(256) void out_reduce_k(
    const float* __restrict__ part, const float* __restrict__ bo,
    float* __restrict__ out) {
  int g = blockIdx.x * 256 + threadIdx.x;
  if (g >= BS * DIM) return;
  int b = g / DIM, c = g - b * DIM;
  float s = 0.f;
  for (int kc = 0; kc < NKC; ++kc) s += part[((size_t)kc * BS + b) * DIM + c];
  out[g] = s + bo[c];
}

// ---------------------------------------------------------------------------
extern "C" void kernel_launch(void* const* d_in, const int* in_sizes, int n_in,
                              void* d_out, int out_size, void* d_ws, size_t ws_size,
                              hipStream_t stream) {
  const float* x  = (const float*)d_in[0];
  // d_in[1] = start_pos (hardcoded 4095 per problem constants)
  const float* fc = (const float*)d_in[2];
  const float* ck = (const float*)d_in[3];
  const float* cv = (const float*)d_in[4];
  const float* wq = (const float*)d_in[5];
  const float* bq = (const float*)d_in[6];
  const float* wk = (const float*)d_in[7];
  const float* bk = (const float*)d_in[8];
  const float* wv = (const float*)d_in[9];
  const float* bv = (const float*)d_in[10];
  const float* wo = (const float*)d_in[11];
  const float* bo = (const float*)d_in[12];

  float* ws      = (float*)d_ws;
  float* qws     = ws + WS_Q;
  float* kws     = ws + WS_K;
  float* vws     = ws + WS_V;
  float* attn    = ws + WS_ATTN;
  float* scratch = ws + WS_SCRATCH;

  // Phase A: QKV projection (partials: NKC*BS*ODQKV = 29.4 MB)
  qkv_partial_k<<<14 * NKC, 256, 0, stream>>>(x, wq, wk, wv, scratch);
  qkv_reduce_k<<<(BS * (ODQKV / 2) + 255) / 256, 256, 0, stream>>>(
      scratch, bq, bk, bv, fc, qws, kws, vws);

  // Phase B: attention (partials: 64*NPART*(2+HD)*NREP floats ~ 21.3 MB)
  float* pM = scratch;
  float* pL = pM + 64 * NPART * NREP;
  float* pO = pL + 64 * NPART * NREP;
  attn_partial_k<<<BS * NCHB, 512, 0, stream>>>(ck, cv, qws, kws, vws, pM, pL, pO);
  attn_combine_k<<<64, 256, 0, stream>>>(pM, pL, pO, attn);

  // Phase C: output projection (partials: NKC*BS*DIM = 21 MB)
  out_partial_k<<<10 * NKC, 256, 0, stream>>>(attn, wo, scratch);
  out_reduce_k<<<(BS * DIM + 255) / 256, 256, 0, stream>>>(scratch, bo, (float*)d_out);
}

// Round 11
// 163.928 us; speedup vs baseline: 1.0645x; 1.0645x over previous
//
#include <hip/hip_runtime.h>
#include <hip/hip_bf16.h>
#include <math.h>

#define DIM   5120
#define NH    40
#define NKV   8
#define HD    128
#define BS    8
#define KLEN  4096
#define NEWT  4095
#define NREP  5

#define ODQKV 7168          // 5120 + 1024 + 1024 combined output columns
#define NKC   32            // split-K chunks for GEMVs (r7 proven config)
#define KCH   (DIM / NKC)   // 160 rows per chunk

#define NCHUNK 64               // t-chunks per (b,h) = blocks per (b,h)
#define CH_T   (KLEN / NCHUNK)  // 64 rows per block
#define NPART  NCHUNK           // one partial per block
#define KPAD   132              // LDS row stride (16B-aligned, bank-spread)

// workspace layout (in floats)
#define WS_Q       0
#define WS_K       (WS_Q + BS * DIM)        // 40960
#define WS_V       (WS_K + BS * NKV * HD)   // 49152
#define WS_ATTN    (WS_V + BS * NKV * HD)   // 57344
#define WS_SCRATCH (WS_ATTN + BS * DIM)     // 98304  (scratch reused across phases)

// ---------------------------------------------------------------------------
// Phase A: combined QKV GEMV, split-K partials. 2 cols/thread, float2 weight
// loads, x via wave-uniform scalar loads.
// ---------------------------------------------------------------------------
__global__ __launch_bounds__(256) void qkv_partial_k(
    const float* __restrict__ x, const float* __restrict__ wq,
    const float* __restrict__ wk, const float* __restrict__ wv,
    float* __restrict__ part) {
  const int cb = blockIdx.x % 14;
  const int kc = blockIdx.x / 14;
  const int c0 = cb * 512 + threadIdx.x * 2;   // first of 2 owned columns

  const float* w; int OD, j;
  if (c0 < 5120)      { w = wq; OD = 5120; j = c0; }
  else if (c0 < 6144) { w = wk; OD = 1024; j = c0 - 5120; }
  else                { w = wv; OD = 1024; j = c0 - 6144; }

  const int i0 = kc * KCH;
  float ax[BS], ay[BS];
#pragma unroll
  for (int b = 0; b < BS; ++b) { ax[b] = 0.f; ay[b] = 0.f; }

  const float* wp = w + (size_t)i0 * OD + j;
  const float* xp = x + i0;
#pragma unroll 4
  for (int ii = 0; ii < KCH; ++ii) {
    const float2 wv2 = *(const float2*)&wp[(size_t)ii * OD];
#pragma unroll
    for (int b = 0; b < BS; ++b) {
      const float xb = xp[b * DIM + ii];   // wave-uniform -> scalar load
      ax[b] = fmaf(xb, wv2.x, ax[b]);
      ay[b] = fmaf(xb, wv2.y, ay[b]);
    }
  }
#pragma unroll
  for (int b = 0; b < BS; ++b)
    *(float2*)&part[((size_t)kc * BS + b) * ODQKV + c0] = make_float2(ax[b], ay[b]);
}

// ---------------------------------------------------------------------------
// Phase A2: reduce partials, add bias, apply RoPE (pos 4095), fold 1/sqrt(128)
// into q.
// ---------------------------------------------------------------------------
__global__ __launch_bounds__(256) void qkv_reduce_k(
    const float* __restrict__ part, const float* __restrict__ bq,
    const float* __restrict__ bk, const float* __restrict__ bv,
    const float* __restrict__ fc, float* __restrict__ qws,
    float* __restrict__ kws, float* __restrict__ vws) {
  int g = blockIdx.x * 256 + threadIdx.x;
  if (g >= BS * (ODQKV / 2)) return;
  int b  = g / (ODQKV / 2);
  int cp = g - b * (ODQKV / 2);
  int c0 = cp * 2;

  float sx = 0.f, sy = 0.f;
  for (int kc = 0; kc < NKC; ++kc) {
    const float2 p = *(const float2*)&part[((size_t)kc * BS + b) * ODQKV + c0];
    sx += p.x; sy += p.y;
  }

  const float scale = 0.088388347648318447f;  // 1/sqrt(128)
  if (c0 < 5120) {
    sx += bq[c0]; sy += bq[c0 + 1];
    int jf = (c0 & 127) >> 1;
    float cs = fc[2 * jf], sn = fc[2 * jf + 1];
    qws[b * DIM + c0]     = (sx * cs - sy * sn) * scale;
    qws[b * DIM + c0 + 1] = (sx * sn + sy * cs) * scale;
  } else if (c0 < 6144) {
    int jj = c0 - 5120;
    sx += bk[jj]; sy += bk[jj + 1];
    int jf = (jj & 127) >> 1;
    float cs = fc[2 * jf], sn = fc[2 * jf + 1];
    kws[b * NKV * HD + jj]     = sx * cs - sy * sn;
    kws[b * NKV * HD + jj + 1] = sx * sn + sy * cs;
  } else {
    int jj = c0 - 6144;
    vws[b * NKV * HD + jj]     = sx + bv[jj];
    vws[b * NKV * HD + jj + 1] = sy + bv[jj + 1];
  }
}

// ---------------------------------------------------------------------------
// Phase B: flash-decode partials, TRANSPOSED score phase (no shuffle trees):
//   stage: K chunk (64 rows) -> padded LDS [64][KPAD] (reg-staged, coalesced)
//   P1: lane=row, wave owns 32 d-cols; per-lane FMA dot, q via s_loads;
//       4 wave-partials summed through LDS. Zero cross-lane ops.
//   P2: block softmax (segment max/sum) on 64x5 scores in LDS
//   P3: V streamed from global (dependency-free FMA), p broadcast from LDS
// Block = (b,h,chunk of 64 t), 4 waves. t=4095 K/V from fresh kws/vws.
// ---------------------------------------------------------------------------
__global__ __launch_bounds__(256) void attn_partial_k(
    const float* __restrict__ ck, const float* __restrict__ cv,
    const float* __restrict__ qws, const float* __restrict__ kws,
    const float* __restrict__ vws, float* __restrict__ pM,
    float* __restrict__ pL, float* __restrict__ pO) {
  const int blk   = blockIdx.x;
  const int chunk = blk & (NCHUNK - 1);
  const int bh    = blk / NCHUNK;
  const int h     = bh & (NKV - 1);
  const int b     = bh / NKV;
  const int tid   = threadIdx.x;
  const int w     = tid >> 6;
  const int lane  = tid & 63;
  const int t0    = chunk * CH_T;

  __shared__ float K_lds[CH_T * KPAD];       // 33 KB; aliased as smO in P3
  __shared__ float spart[4 * CH_T * NREP];   // wave dot partials (5 KB)
  __shared__ float s_lds[CH_T * NREP];       // scores, then p-values
  __shared__ float red[NREP * 8];
  __shared__ float Msh[NREP], Lsh[NREP];

  // ---- stage K rows into padded LDS (coalesced global float4 reads) ----
  {
    const int rb = tid >> 5;             // 0..7
    const int d0 = (tid & 31) * 4;
#pragma unroll
    for (int p = 0; p < 8; ++p) {
      const int row = p * 8 + rb;
      const int tg  = t0 + row;
      const float* src = (tg == NEWT)
          ? &kws[(b * NKV + h) * HD]
          : &ck[(((size_t)b * KLEN + tg) * NKV + h) * HD];
      *(float4*)&K_lds[row * KPAD + d0] = *(const float4*)&src[d0];
    }
  }
  __syncthreads();

  // ---- P1: transposed dot. lane = row, wave w owns d in [32w, 32w+32) ----
  {
    const int row = lane;
    float s[NREP];
#pragma unroll
    for (int r = 0; r < NREP; ++r) s[r] = 0.f;
    const float* qb = &qws[b * DIM + h * NREP * HD];   // wave-uniform base
    const int dbase = w * 32;
#pragma unroll
    for (int c = 0; c < 8; ++c) {
      const int d0 = dbase + c * 4;
      const float4 k4 = *(const float4*)&K_lds[row * KPAD + d0];
#pragma unroll
      for (int r = 0; r < NREP; ++r) {
        const float4 q4 = *(const float4*)&qb[r * HD + d0];  // uniform->s_load
        s[r] = fmaf(k4.x, q4.x,
               fmaf(k4.y, q4.y,
               fmaf(k4.z, q4.z,
               fmaf(k4.w, q4.w, s[r]))));
      }
    }
#pragma unroll
    for (int r = 0; r < NREP; ++r)
      spart[(w * CH_T + row) * NREP + r] = s[r];
  }
  __syncthreads();

  // sum the 4 wave partials -> raw scores
  for (int idx = tid; idx < CH_T * NREP; idx += 256)
    s_lds[idx] = spart[idx] + spart[CH_T * NREP + idx]
               + spart[2 * CH_T * NREP + idx] + spart[3 * CH_T * NREP + idx];
  __syncthreads();

  // ---- P2: block softmax ----
  if (tid < NREP * 8) {                      // (a) segment maxima (8 rows/seg)
    const int rr = tid >> 3, seg = tid & 7;
    float mx = -1e30f;
#pragma unroll
    for (int k = 0; k < 8; ++k) mx = fmaxf(mx, s_lds[(seg * 8 + k) * NREP + rr]);
    red[tid] = mx;
  }
  __syncthreads();
  if (tid < NREP) {                          // (b) final max
    float mx = red[tid * 8];
#pragma unroll
    for (int k = 1; k < 8; ++k) mx = fmaxf(mx, red[tid * 8 + k]);
    Msh[tid] = mx;
  }
  __syncthreads();
  for (int idx = tid; idx < CH_T * NREP; idx += 256)   // (c) p = exp(s-M)
    s_lds[idx] = __expf(s_lds[idx] - Msh[idx % NREP]);
  __syncthreads();
  if (tid < NREP * 8) {                      // (d) segment sums
    const int rr = tid >> 3, seg = tid & 7;
    float sm = 0.f;
#pragma unroll
    for (int k = 0; k < 8; ++k) sm += s_lds[(seg * 8 + k) * NREP + rr];
    red[tid] = sm;
  }
  __syncthreads();
  if (tid < NREP) {                          // (e) row sum
    float L = 0.f;
#pragma unroll
    for (int k = 0; k < 8; ++k) L += red[tid * 8 + k];
    Lsh[tid] = L;
  }

  // ---- P3: PV streaming from global (16-lane groups, 4 rows/pass) ----
  const int g  = lane >> 4;        // group: row within a 4-row pass
  const int sl = lane & 15;        // owns d-range [8*sl, 8*sl+8)
  float o[NREP][8];
#pragma unroll
  for (int rr = 0; rr < NREP; ++rr)
#pragma unroll
    for (int j = 0; j < 8; ++j) o[rr][j] = 0.f;

  const bool tailw = (chunk == NCHUNK - 1) && (w == 3);  // rows 60..63
  const int  jmax  = tailw ? 3 : 4;
  {
    const float* vp = cv + (((size_t)b * KLEN + (t0 + w * 16 + g)) * NKV + h) * HD + 8 * sl;
#pragma unroll
    for (int j = 0; j < jmax; ++j) {
      const float4 va = *(const float4*)vp;
      const float4 vb = *(const float4*)(vp + 4);
      const int r = w * 16 + j * 4 + g;
      float p[NREP];
#pragma unroll
      for (int rr = 0; rr < NREP; ++rr) p[rr] = s_lds[r * NREP + rr];  // bcast
      const float vv[8] = {va.x, va.y, va.z, va.w, vb.x, vb.y, vb.z, vb.w};
#pragma unroll
      for (int rr = 0; rr < NREP; ++rr)
#pragma unroll
        for (int jj = 0; jj < 8; ++jj) o[rr][jj] = fmaf(p[rr], vv[jj], o[rr][jj]);
      vp += (size_t)4 * NKV * HD;
    }
    if (tailw) {
      const int r  = 60 + g;
      const int tg = t0 + r;                 // 4092..4095
      const float* vr = (tg == NEWT) ? (vws + (b * NKV + h) * HD)
                                     : (cv + (((size_t)b * KLEN + tg) * NKV + h) * HD);
      const float4 va = *(const float4*)(vr + 8 * sl);
      const float4 vb = *(const float4*)(vr + 8 * sl + 4);
      float p[NREP];
#pragma unroll
      for (int rr = 0; rr < NREP; ++rr) p[rr] = s_lds[r * NREP + rr];
      const float vv[8] = {va.x, va.y, va.z, va.w, vb.x, vb.y, vb.z, vb.w};
#pragma unroll
      for (int rr = 0; rr < NREP; ++rr)
#pragma unroll
        for (int jj = 0; jj < 8; ++jj) o[rr][jj] = fmaf(p[rr], vv[jj], o[rr][jj]);
    }
  }

  // merge 4 groups: plain sums (p normalized to the shared block max)
#pragma unroll
  for (int off = 16; off <= 32; off <<= 1) {
#pragma unroll
    for (int rr = 0; rr < NREP; ++rr)
#pragma unroll
      for (int jj = 0; jj < 8; ++jj) o[rr][jj] += __shfl_xor(o[rr][jj], off, 64);
  }

  __syncthreads();                            // K_lds reads done; safe to alias
  float* smO = K_lds;                         // alias: [4][NREP][HD]
  if (g == 0) {
#pragma unroll
    for (int rr = 0; rr < NREP; ++rr) {
      float* sp = &smO[(w * NREP + rr) * HD + 8 * sl];
      *(float4*)sp       = make_float4(o[rr][0], o[rr][1], o[rr][2], o[rr][3]);
      *(float4*)(sp + 4) = make_float4(o[rr][4], o[rr][5], o[rr][6], o[rr][7]);
    }
  }
  __syncthreads();

  if (tid < HD) {
    const int d  = tid;
    const int pb = bh * NCHUNK + chunk;
#pragma unroll
    for (int rr = 0; rr < NREP; ++rr) {
      float acc = smO[rr * HD + d] + smO[(NREP + rr) * HD + d]
                + smO[(2 * NREP + rr) * HD + d] + smO[(3 * NREP + rr) * HD + d];
      pO[((size_t)pb * NREP + rr) * HD + d] = acc;
      if (d == 0) { pM[pb * NREP + rr] = Msh[rr]; pL[pb * NREP + rr] = Lsh[rr]; }
    }
  }
}

// ---------------------------------------------------------------------------
// Phase B2: combine NPART partials per (b,h) with exp rescale.
// ---------------------------------------------------------------------------
__global__ __launch_bounds__(256) void attn_combine_k(
    const float* __restrict__ pM, const float* __restrict__ pL,
    const float* __restrict__ pO, float* __restrict__ attn) {
  const int bh  = blockIdx.x;
  const int h   = bh & (NKV - 1);
  const int b   = bh / NKV;
  const int tid = threadIdx.x;
  __shared__ float ml[NREP * NPART], ll[NREP * NPART];
  __shared__ float wgt[NREP * NPART];
  __shared__ float Linv[NREP];

  for (int idx = tid; idx < NREP * NPART; idx += 256) {
    int r = idx / NPART, w = idx - r * NPART;
    ml[idx] = pM[(bh * NPART + w) * NREP + r];
    ll[idx] = pL[(bh * NPART + w) * NREP + r];
  }
  __syncthreads();
  for (int idx = tid; idx < NREP * NPART; idx += 256) {
    int r = idx / NPART;
    float M = -1e30f;
    for (int w = 0; w < NPART; ++w) M = fmaxf(M, ml[r * NPART + w]);
    float e = __expf(ml[idx] - M);
    wgt[idx] = e;
    ll[idx] *= e;
  }
  __syncthreads();
  if (tid < NREP) {
    float L = 0.f;
    for (int w = 0; w < NPART; ++w) L += ll[tid * NPART + w];
    Linv[tid] = 1.f / L;
  }
  __syncthreads();

  for (int oidx = tid; oidx < NREP * HD; oidx += 256) {
    int r = oidx >> 7, d = oidx & 127;
    float acc = 0.f;
    for (int w = 0; w < NPART; ++w)
      acc += wgt[r * NPART + w] * pO[((size_t)(bh * NPART + w) * NREP + r) * HD + d];
    attn[b * DIM + (h * NREP + r) * HD + d] = acc * Linv[r];
  }
}

// ---------------------------------------------------------------------------
// Phase C: output projection GEMV (split-K, 2 cols/thread) + reduce with bias.
// ---------------------------------------------------------------------------
__global__ __launch_bounds__(256) void out_partial_k(
    const float* __restrict__ attn, const float* __restrict__ wo,
    float* __restrict__ part) {
  const int cb = blockIdx.x % 10;
  const int kc = blockIdx.x / 10;
  const int c0 = cb * 512 + threadIdx.x * 2;

  const int i0 = kc * KCH;
  float ax[BS], ay[BS];
#pragma unroll
  for (int b = 0; b < BS; ++b) { ax[b] = 0.f; ay[b] = 0.f; }

  const float* wp = wo + (size_t)i0 * DIM + c0;
  const float* xp = attn + i0;
#pragma unroll 4
  for (int ii = 0; ii < KCH; ++ii) {
    const float2 wv2 = *(const float2*)&wp[(size_t)ii * DIM];
#pragma unroll
    for (int b = 0; b < BS; ++b) {
      const float xb = xp[b * DIM + ii];   // wave-uniform -> scalar load
      ax[b] = fmaf(xb, wv2.x, ax[b]);
      ay[b] = fmaf(xb, wv2.y, ay[b]);
    }
  }
#pragma unroll
  for (int b = 0; b < BS; ++b)
    *(float2*)&part[((size_t)kc * BS + b) * DIM + c0] = make_float2(ax[b], ay[b]);
}

__global__ __launch_bounds__(256) void out_reduce_k(
    const float* __restrict__ part, const float* __restrict__ bo,
    float* __restrict__ out) {
  int g = blockIdx.x * 256 + threadIdx.x;
  if (g >= BS * DIM) return;
  int b = g / DIM, c = g - b * DIM;
  float s = 0.f;
  for (int kc = 0; kc < NKC; ++kc) s += part[((size_t)kc * BS + b) * DIM + c];
  out[g] = s + bo[c];
}

// ---------------------------------------------------------------------------
extern "C" void kernel_launch(void* const* d_in, const int* in_sizes, int n_in,
                              void* d_out, int out_size, void* d_ws, size_t ws_size,
                              hipStream_t stream) {
  const float* x  = (const float*)d_in[0];
  // d_in[1] = start_pos (hardcoded 4095 per problem constants)
  const float* fc = (const float*)d_in[2];
  const float* ck = (const float*)d_in[3];
  const float* cv = (const float*)d_in[4];
  const float* wq = (const float*)d_in[5];
  const float* bq = (const float*)d_in[6];
  const float* wk = (const float*)d_in[7];
  const float* bk = (const float*)d_in[8];
  const float* wv = (const float*)d_in[9];
  const float* bv = (const float*)d_in[10];
  const float* wo = (const float*)d_in[11];
  const float* bo = (const float*)d_in[12];

  float* ws      = (float*)d_ws;
  float* qws     = ws + WS_Q;
  float* kws     = ws + WS_K;
  float* vws     = ws + WS_V;
  float* attn    = ws + WS_ATTN;
  float* scratch = ws + WS_SCRATCH;

  // Phase A: QKV projection
  qkv_partial_k<<<14 * NKC, 256, 0, stream>>>(x, wq, wk, wv, scratch);
  qkv_reduce_k<<<(BS * (ODQKV / 2) + 255) / 256, 256, 0, stream>>>(
      scratch, bq, bk, bv, fc, qws, kws, vws);

  // Phase B: attention (scratch reused for softmax partials)
  float* pM = scratch;
  float* pL = pM + 64 * NPART * NREP;
  float* pO = pL + 64 * NPART * NREP;
  attn_partial_k<<<64 * NCHUNK, 256, 0, stream>>>(ck, cv, qws, kws, vws, pM, pL, pO);
  attn_combine_k<<<64, 256, 0, stream>>>(pM, pL, pO, attn);

  // Phase C: output projection (scratch reused for GEMV partials)
  out_partial_k<<<10 * NKC, 256, 0, stream>>>(attn, wo, scratch);
  out_reduce_k<<<(BS * DIM + 255) / 256, 256, 0, stream>>>(scratch, bo, (float*)d_out);
}

// Round 12
// 142.965 us; speedup vs baseline: 1.2206x; 1.1466x over previous
//
#include <hip/hip_runtime.h>
#include <hip/hip_bf16.h>
#include <math.h>

#define DIM   5120
#define NH    40
#define NKV   8
#define HD    128
#define BS    8
#define KLEN  4096
#define NEWT  4095
#define NREP  5

#define ODQKV 7168          // 5120 + 1024 + 1024 combined output columns
#define NKC   32            // split-K chunks for GEMVs (r5/r7 proven)
#define KCH   (DIM / NKC)   // 160 rows per chunk

#define NCHUNK 64               // t-chunks per (b,h) = blocks per (b,h)
#define CH_T   (KLEN / NCHUNK)  // 64 rows per block
#define NPART  NCHUNK           // one partial per block

// workspace layout (in floats)
#define WS_Q       0
#define WS_K       (WS_Q + BS * DIM)        // 40960
#define WS_V       (WS_K + BS * NKV * HD)   // 49152
#define WS_ATTN    (WS_V + BS * NKV * HD)   // 57344
#define WS_SCRATCH (WS_ATTN + BS * DIM)     // 98304  (scratch reused across phases)

// ---------------------------------------------------------------------------
// Phase A: combined QKV GEMV, split-K partials. 2 cols/thread, float2 weight
// loads, x via wave-uniform scalar loads.
// ---------------------------------------------------------------------------
__global__ __launch_bounds__(256) void qkv_partial_k(
    const float* __restrict__ x, const float* __restrict__ wq,
    const float* __restrict__ wk, const float* __restrict__ wv,
    float* __restrict__ part) {
  const int cb = blockIdx.x % 14;
  const int kc = blockIdx.x / 14;
  const int c0 = cb * 512 + threadIdx.x * 2;   // first of 2 owned columns

  const float* w; int OD, j;
  if (c0 < 5120)      { w = wq; OD = 5120; j = c0; }
  else if (c0 < 6144) { w = wk; OD = 1024; j = c0 - 5120; }
  else                { w = wv; OD = 1024; j = c0 - 6144; }

  const int i0 = kc * KCH;
  float ax[BS], ay[BS];
#pragma unroll
  for (int b = 0; b < BS; ++b) { ax[b] = 0.f; ay[b] = 0.f; }

  const float* wp = w + (size_t)i0 * OD + j;
  const float* xp = x + i0;
#pragma unroll 4
  for (int ii = 0; ii < KCH; ++ii) {
    const float2 wv2 = *(const float2*)&wp[(size_t)ii * OD];
#pragma unroll
    for (int b = 0; b < BS; ++b) {
      const float xb = xp[b * DIM + ii];   // wave-uniform -> scalar load
      ax[b] = fmaf(xb, wv2.x, ax[b]);
      ay[b] = fmaf(xb, wv2.y, ay[b]);
    }
  }
#pragma unroll
  for (int b = 0; b < BS; ++b)
    *(float2*)&part[((size_t)kc * BS + b) * ODQKV + c0] = make_float2(ax[b], ay[b]);
}

// ---------------------------------------------------------------------------
// Phase A2: reduce partials, add bias, apply RoPE (pos 4095), fold 1/sqrt(128)
// into q.
// ---------------------------------------------------------------------------
__global__ __launch_bounds__(256) void qkv_reduce_k(
    const float* __restrict__ part, const float* __restrict__ bq,
    const float* __restrict__ bk, const float* __restrict__ bv,
    const float* __restrict__ fc, float* __restrict__ qws,
    float* __restrict__ kws, float* __restrict__ vws) {
  int g = blockIdx.x * 256 + threadIdx.x;
  if (g >= BS * (ODQKV / 2)) return;
  int b  = g / (ODQKV / 2);
  int cp = g - b * (ODQKV / 2);
  int c0 = cp * 2;

  float sx = 0.f, sy = 0.f;
  for (int kc = 0; kc < NKC; ++kc) {
    const float2 p = *(const float2*)&part[((size_t)kc * BS + b) * ODQKV + c0];
    sx += p.x; sy += p.y;
  }

  const float scale = 0.088388347648318447f;  // 1/sqrt(128)
  if (c0 < 5120) {
    sx += bq[c0]; sy += bq[c0 + 1];
    int jf = (c0 & 127) >> 1;
    float cs = fc[2 * jf], sn = fc[2 * jf + 1];
    qws[b * DIM + c0]     = (sx * cs - sy * sn) * scale;
    qws[b * DIM + c0 + 1] = (sx * sn + sy * cs) * scale;
  } else if (c0 < 6144) {
    int jj = c0 - 5120;
    sx += bk[jj]; sy += bk[jj + 1];
    int jf = (jj & 127) >> 1;
    float cs = fc[2 * jf], sn = fc[2 * jf + 1];
    kws[b * NKV * HD + jj]     = sx * cs - sy * sn;
    kws[b * NKV * HD + jj + 1] = sx * sn + sy * cs;
  } else {
    int jj = c0 - 6144;
    vws[b * NKV * HD + jj]     = sx + bv[jj];
    vws[b * NKV * HD + jj + 1] = sy + bv[jj + 1];
  }
}

// ---------------------------------------------------------------------------
// Phase B: flash-decode partials, 3-phase + V-REGISTER-PRELOAD:
//   preload: ALL of this wave's V (8x dwordx4 = 8 KB/wave) issued before P1,
//            so K and V streams are concurrently in flight (GEMV-like MLP).
//   P1: K from global, 16-lane-group dot + 4-stage shuffle -> raw s in LDS
//   P2: block softmax (max, exp, sums) in LDS
//   P3: o += p*V from REGISTERS (no loads), p broadcast from LDS
// Block = (b,h,chunk of 64 t), 4 waves x 16 rows. The 4th-pass row uses a
// pointer-select so t=4095 reads fresh kws/vws (no divergent tail loop).
// ---------------------------------------------------------------------------
__global__ __launch_bounds__(256) void attn_partial_k(
    const float* __restrict__ ck, const float* __restrict__ cv,
    const float* __restrict__ qws, const float* __restrict__ kws,
    const float* __restrict__ vws, float* __restrict__ pM,
    float* __restrict__ pL, float* __restrict__ pO) {
  const int blk   = blockIdx.x;
  const int chunk = blk & (NCHUNK - 1);
  const int bh    = blk / NCHUNK;
  const int h     = bh & (NKV - 1);
  const int b     = bh / NKV;
  const int tid   = threadIdx.x;
  const int w     = tid >> 6;
  const int lane  = tid & 63;
  const int g     = lane >> 4;     // row within a 4-row pass
  const int sl    = lane & 15;     // owns d-range [8*sl, 8*sl+8)
  const int t0    = chunk * CH_T;
  const int rw0   = w * 16;        // wave's first local row

  __shared__ float s_lds[CH_T * NREP];    // raw scores, then p-values
  __shared__ float red[NREP * 8];
  __shared__ float Msh[NREP], Lsh[NREP];
  __shared__ float smO[4 * NREP * HD];    // per-wave output partials (10 KB)

  // row index of the 4th pass for this (w,g); only row 4095 needs fresh k/v
  const int r3  = rw0 + 12 + g;
  const int tg3 = t0 + r3;

  // ---- V preload: issue all 8 dwordx4 NOW (overlap with P1's K stream) ----
  float4 vA[4], vB[4];
  {
    const float* vp = cv + (((size_t)b * KLEN + (t0 + rw0 + g)) * NKV + h) * HD + 8 * sl;
#pragma unroll
    for (int j = 0; j < 3; ++j) {
      vA[j] = *(const float4*)vp;
      vB[j] = *(const float4*)(vp + 4);
      vp += (size_t)4 * NKV * HD;
    }
    const float* vr3 = (tg3 == NEWT) ? (vws + (b * NKV + h) * HD)
                                     : (cv + (((size_t)b * KLEN + tg3) * NKV + h) * HD);
    vA[3] = *(const float4*)(vr3 + 8 * sl);
    vB[3] = *(const float4*)(vr3 + 8 * sl + 4);
  }

  float4 qa[NREP], qb[NREP];
#pragma unroll
  for (int rr = 0; rr < NREP; ++rr) {
    const float* qp = &qws[b * DIM + (h * NREP + rr) * HD + 8 * sl];
    qa[rr] = *(const float4*)qp;
    qb[rr] = *(const float4*)(qp + 4);
  }

  // ---- P1: scores (K from global, 4-stage 16-lane shuffle reduce) ----
  {
    const float* kp = ck + (((size_t)b * KLEN + (t0 + rw0 + g)) * NKV + h) * HD + 8 * sl;
#pragma unroll
    for (int i = 0; i < 4; ++i) {
      const float* kr = kp;
      if (i == 3 && tg3 == NEWT) kr = kws + (b * NKV + h) * HD + 8 * sl;
      const float4 ka = *(const float4*)kr;
      const float4 kb = *(const float4*)(kr + 4);
      kp += (size_t)4 * NKV * HD;
      float s[NREP];
#pragma unroll
      for (int rr = 0; rr < NREP; ++rr) {
        s[rr] = qa[rr].x * ka.x + qa[rr].y * ka.y + qa[rr].z * ka.z + qa[rr].w * ka.w
              + qb[rr].x * kb.x + qb[rr].y * kb.y + qb[rr].z * kb.z + qb[rr].w * kb.w;
      }
#pragma unroll
      for (int off = 1; off < 16; off <<= 1) {
#pragma unroll
        for (int rr = 0; rr < NREP; ++rr) s[rr] += __shfl_xor(s[rr], off, 64);
      }
      const int tl = rw0 + 4 * i + g;
      float sv = (sl == 0) ? s[0] : (sl == 1) ? s[1] : (sl == 2) ? s[2]
               : (sl == 3) ? s[3] : s[4];
      if (sl < NREP) s_lds[tl * NREP + sl] = sv;
    }
  }
  // pin V-load issue to no later than end of P1 (keep regs live across barrier)
#pragma unroll
  for (int j = 0; j < 4; ++j)
    asm volatile("" :: "v"(vA[j].x), "v"(vA[j].w), "v"(vB[j].x), "v"(vB[j].w));
  __syncthreads();

  // ---- P2: block softmax over 64 rows x 5 heads ----
  if (tid < NREP * 8) {                      // (a) segment maxima (8 rows/seg)
    const int rr = tid >> 3, seg = tid & 7;
    float mx = -1e30f;
#pragma unroll
    for (int k = 0; k < 8; ++k) mx = fmaxf(mx, s_lds[(seg * 8 + k) * NREP + rr]);
    red[tid] = mx;
  }
  __syncthreads();
  if (tid < NREP) {                          // (b) final max
    float mx = red[tid * 8];
#pragma unroll
    for (int k = 1; k < 8; ++k) mx = fmaxf(mx, red[tid * 8 + k]);
    Msh[tid] = mx;
  }
  __syncthreads();
  for (int idx = tid; idx < CH_T * NREP; idx += 256)   // (c) p = exp(s-M)
    s_lds[idx] = __expf(s_lds[idx] - Msh[idx % NREP]);
  __syncthreads();
  if (tid < NREP * 8) {                      // (d) segment sums
    const int rr = tid >> 3, seg = tid & 7;
    float sm = 0.f;
#pragma unroll
    for (int k = 0; k < 8; ++k) sm += s_lds[(seg * 8 + k) * NREP + rr];
    red[tid] = sm;
  }
  __syncthreads();
  if (tid < NREP) {                          // (e) row sum
    float L = 0.f;
#pragma unroll
    for (int k = 0; k < 8; ++k) L += red[tid * 8 + k];
    Lsh[tid] = L;
  }

  // ---- P3: PV from registers (zero loads) ----
  float o[NREP][8];
#pragma unroll
  for (int rr = 0; rr < NREP; ++rr)
#pragma unroll
    for (int jj = 0; jj < 8; ++jj) o[rr][jj] = 0.f;

#pragma unroll
  for (int j = 0; j < 4; ++j) {
    const int r = rw0 + j * 4 + g;
    float p[NREP];
#pragma unroll
    for (int rr = 0; rr < NREP; ++rr) p[rr] = s_lds[r * NREP + rr];  // bcast
    const float vv[8] = {vA[j].x, vA[j].y, vA[j].z, vA[j].w,
                         vB[j].x, vB[j].y, vB[j].z, vB[j].w};
#pragma unroll
    for (int rr = 0; rr < NREP; ++rr)
#pragma unroll
      for (int jj = 0; jj < 8; ++jj) o[rr][jj] = fmaf(p[rr], vv[jj], o[rr][jj]);
  }

  // merge 4 groups: plain sums (p normalized to the shared block max)
#pragma unroll
  for (int off = 16; off <= 32; off <<= 1) {
#pragma unroll
    for (int rr = 0; rr < NREP; ++rr)
#pragma unroll
      for (int jj = 0; jj < 8; ++jj) o[rr][jj] += __shfl_xor(o[rr][jj], off, 64);
  }

  if (g == 0) {
#pragma unroll
    for (int rr = 0; rr < NREP; ++rr) {
      float* sp = &smO[(w * NREP + rr) * HD + 8 * sl];
      *(float4*)sp       = make_float4(o[rr][0], o[rr][1], o[rr][2], o[rr][3]);
      *(float4*)(sp + 4) = make_float4(o[rr][4], o[rr][5], o[rr][6], o[rr][7]);
    }
  }
  __syncthreads();

  if (tid < HD) {
    const int d  = tid;
    const int pb = bh * NPART + chunk;
#pragma unroll
    for (int rr = 0; rr < NREP; ++rr) {
      float acc = smO[rr * HD + d] + smO[(NREP + rr) * HD + d]
                + smO[(2 * NREP + rr) * HD + d] + smO[(3 * NREP + rr) * HD + d];
      pO[((size_t)pb * NREP + rr) * HD + d] = acc;
      if (d == 0) { pM[pb * NREP + rr] = Msh[rr]; pL[pb * NREP + rr] = Lsh[rr]; }
    }
  }
}

// ---------------------------------------------------------------------------
// Phase B2: combine NPART partials per (b,h,r). 320 blocks x 128 threads.
// ---------------------------------------------------------------------------
__global__ __launch_bounds__(128) void attn_combine_k(
    const float* __restrict__ pM, const float* __restrict__ pL,
    const float* __restrict__ pO, float* __restrict__ attn) {
  const int bhr = blockIdx.x;          // 64 * NREP
  const int r   = bhr % NREP;
  const int bh  = bhr / NREP;
  const int h   = bh & (NKV - 1);
  const int b   = bh / NKV;
  const int d   = threadIdx.x;         // 0..127

  __shared__ float ml[NPART], ll[NPART];
  if (d < NPART) {
    ml[d] = pM[(bh * NPART + d) * NREP + r];
    ll[d] = pL[(bh * NPART + d) * NREP + r];
  }
  __syncthreads();

  float M = -1e30f;
  for (int w2 = 0; w2 < NPART; ++w2) M = fmaxf(M, ml[w2]);
  float L = 0.f, acc = 0.f;
  for (int w2 = 0; w2 < NPART; ++w2) {
    const float e = __expf(ml[w2] - M);
    L  = fmaf(e, ll[w2], L);
    acc = fmaf(e, pO[((size_t)(bh * NPART + w2) * NREP + r) * HD + d], acc);
  }
  attn[b * DIM + (h * NREP + r) * HD + d] = acc / L;
}

// ---------------------------------------------------------------------------
// Phase C: output projection GEMV (split-K, 2 cols/thread) + reduce with bias.
// ---------------------------------------------------------------------------
__global__ __launch_bounds__(256) void out_partial_k(
    const float* __restrict__ attn, const float* __restrict__ wo,
    float* __restrict__ part) {
  const int cb = blockIdx.x % 10;
  const int kc = blockIdx.x / 10;
  const int c0 = cb * 512 + threadIdx.x * 2;

  const int i0 = kc * KCH;
  float ax[BS], ay[BS];
#pragma unroll
  for (int b = 0; b < BS; ++b) { ax[b] = 0.f; ay[b] = 0.f; }

  const float* wp = wo + (size_t)i0 * DIM + c0;
  const float* xp = attn + i0;
#pragma unroll 4
  for (int ii = 0; ii < KCH; ++ii) {
    const float2 wv2 = *(const float2*)&wp[(size_t)ii * DIM];
#pragma unroll
    for (int b = 0; b < BS; ++b) {
      const float xb = xp[b * DIM + ii];   // wave-uniform -> scalar load
      ax[b] = fmaf(xb, wv2.x, ax[b]);
      ay[b] = fmaf(xb, wv2.y, ay[b]);
    }
  }
#pragma unroll
  for (int b = 0; b < BS; ++b)
    *(float2*)&part[((size_t)kc * BS + b) * DIM + c0] = make_float2(ax[b], ay[b]);
}

__global__ __launch_bounds__(256) void out_reduce_k(
    const float* __restrict__ part, const float* __restrict__ bo,
    float* __restrict__ out) {
  int g = blockIdx.x * 256 + threadIdx.x;
  if (g >= BS * DIM) return;
  int b = g / DIM, c = g - b * DIM;
  float s = 0.f;
  for (int kc = 0; kc < NKC; ++kc) s += part[((size_t)kc * BS + b) * DIM + c];
  out[g] = s + bo[c];
}

// ---------------------------------------------------------------------------
extern "C" void kernel_launch(void* const* d_in, const int* in_sizes, int n_in,
                              void* d_out, int out_size, void* d_ws, size_t ws_size,
                              hipStream_t stream) {
  const float* x  = (const float*)d_in[0];
  // d_in[1] = start_pos (hardcoded 4095 per problem constants)
  const float* fc = (const float*)d_in[2];
  const float* ck = (const float*)d_in[3];
  const float* cv = (const float*)d_in[4];
  const float* wq = (const float*)d_in[5];
  const float* bq = (const float*)d_in[6];
  const float* wk = (const float*)d_in[7];
  const float* bk = (const float*)d_in[8];
  const float* wv = (const float*)d_in[9];
  const float* bv = (const float*)d_in[10];
  const float* wo = (const float*)d_in[11];
  const float* bo = (const float*)d_in[12];

  float* ws      = (float*)d_ws;
  float* qws     = ws + WS_Q;
  float* kws     = ws + WS_K;
  float* vws     = ws + WS_V;
  float* attn    = ws + WS_ATTN;
  float* scratch = ws + WS_SCRATCH;

  // Phase A: QKV projection
  qkv_partial_k<<<14 * NKC, 256, 0, stream>>>(x, wq, wk, wv, scratch);
  qkv_reduce_k<<<(BS * (ODQKV / 2) + 255) / 256, 256, 0, stream>>>(
      scratch, bq, bk, bv, fc, qws, kws, vws);

  // Phase B: attention (scratch reused for softmax partials)
  float* pM = scratch;
  float* pL = pM + 64 * NPART * NREP;
  float* pO = pL + 64 * NPART * NREP;
  attn_partial_k<<<64 * NCHUNK, 256, 0, stream>>>(ck, cv, qws, kws, vws, pM, pL, pO);
  attn_combine_k<<<64 * NREP, 128, 0, stream>>>(pM, pL, pO, attn);

  // Phase C: output projection (scratch reused for GEMV partials)
  out_partial_k<<<10 * NKC, 256, 0, stream>>>(attn, wo, scratch);
  out_reduce_k<<<(BS * DIM + 255) / 256, 256, 0, stream>>>(scratch, bo, (float*)d_out);
}